// Round 1
// baseline (221.660 us; speedup 1.0000x reference)
//
#include <hip/hip_runtime.h>
#include <hip/hip_bf16.h>

// Reference output is stop_gradient(1 - y) + y computed in fp32, where y is a
// softmax probability in (0,1]. fl(fl(1-y)+y) == 1.0f within ~2^-23 for all
// representable y in [0,1] — far inside the 2e-2 absmax threshold. The whole
// gather/segment-softmax pipeline is dead code for the forward value, so the
// optimal kernel is a 4 MiB fill of 1.0f.

__global__ void fill_ones_f4(float4* __restrict__ out, int n4) {
    int i = blockIdx.x * blockDim.x + threadIdx.x;
    if (i < n4) {
        out[i] = make_float4(1.0f, 1.0f, 1.0f, 1.0f);
    }
}

__global__ void fill_ones_tail(float* __restrict__ out, int start, int n) {
    int i = start + blockIdx.x * blockDim.x + threadIdx.x;
    if (i < n) {
        out[i] = 1.0f;
    }
}

extern "C" void kernel_launch(void* const* d_in, const int* in_sizes, int n_in,
                              void* d_out, int out_size, void* d_ws, size_t ws_size,
                              hipStream_t stream) {
    (void)d_in; (void)in_sizes; (void)n_in; (void)d_ws; (void)ws_size;

    float* out = (float*)d_out;
    int n4 = out_size >> 2;           // out_size = 1048576 -> n4 = 262144
    if (n4 > 0) {
        int block = 256;
        int grid = (n4 + block - 1) / block;
        fill_ones_f4<<<grid, block, 0, stream>>>((float4*)out, n4);
    }
    int done = n4 << 2;
    int rem = out_size - done;        // 0 for this problem, kept for safety
    if (rem > 0) {
        fill_ones_tail<<<1, 64, 0, stream>>>(out, done, out_size);
    }
}